// Round 6
// baseline (99.553 us; speedup 1.0000x reference)
//
#include <hip/hip_runtime.h>

// Two-kernel pipeline: deterministic (atomic-free) bucket scatter +
// degree-sorted LDS solve with double-buffered v.
//
// R13 == R12 resubmitted verbatim: R12's bench died with "MI355X container
// failed twice" (infra flake, no pytest verdict, no profile). Audit found no
// deadlock (no spin anywhere), no OOB, LDS 118.1 KB < 160 KB, and the same
// cross-kernel visibility mechanism R11 verified (absmax 0.0).
//
// R12 changes vs R11 (91.6 us; remaining overhead = 8192 global atomicAdds
// on one cache line gating all bucket stores, serial tid==0 64-bin prefix
// loop, 2 barriers per k-iter):
//  - Scatter: per-(block,graph) private 128-slot bucket regions. Slots come
//    from LDS histogram atomics only; counts stored with plain writes to
//    g_cnt[b][g]. ZERO global atomics, zero cross-launch device state to
//    reset, stores issue as soon as the block's own LDS atomics resolve.
//    P(Poisson(64) > 128) ~ 1e-12 -> no edge loss.
//  - Solve: streams the 128 KB region with count-masked validity (invalid
//    upper-half waves execz-skip); wave-parallel __shfl_up prefix scan for
//    the degree counting-sort; v double-buffered -> ONE barrier per k-iter
//    (gather reads v[cur], writes go to v[cur^1], barrier orders writes
//    before the next iteration's gathers).
//  - Verified invariants kept: prescaled u16 byte offsets, zero-prefilled
//    CSR rows + degree masking, register-staged neighbor lists, y computed
//    in scatter (loads issued ahead of the LDS-atomic phase).

#define BMAX   32
#define NMAX   1024
#define REG_E  48                 // per-node in-edge cap (Poisson(16); P(>48) ~ 1e-10)
#define RE_U32 (REG_E / 2)
#define TPB    1024
#define SCT    512                // scatter threads/block (1 int4 each)
#define SCB    256                // scatter blocks (E / (SCT*4))
#define SLOT   128                // per-(block,graph) bucket slots (mean 64)

__device__ __align__(16) unsigned g_bucket[BMAX * SCB * SLOT];  // 4 MB
__device__ int   g_cnt[SCB * BMAX];                             // [block][graph], rewritten each launch
__device__ __align__(16) float g_y[BMAX * NMAX];                // 128 KB

__global__ __launch_bounds__(SCT) void
k_scatter(const int* __restrict__ dst_g, const int* __restrict__ src_g,
          const float* __restrict__ x, const float* __restrict__ W) {
    __shared__ int cnt32[32];
    const int tid = threadIdx.x;
    const int b   = blockIdx.x;

    if (tid < 32) cnt32[tid] = 0;

    // issue all global loads up front (edges + this block's x rows)
    const int  i  = b * SCT + tid;                 // int4 slot; grid covers E/4 exactly
    const int4 d4 = ((const int4*)dst_g)[i];
    const int4 s4 = ((const int4*)src_g)[i];

    const int    sub = tid & 7, grp = tid >> 3;    // 8 lanes per node, 64 nodes/pass
    const float4 wv  = ((const float4*)W)[sub];
    const int    n0  = (b << 7) + grp;             // this block owns 128 nodes
    const int    n1  = n0 + 64;
    const float4 xv0 = ((const float4*)(x + (size_t)n0 * 32))[sub];
    const float4 xv1 = ((const float4*)(x + (size_t)n1 * 32))[sub];

    __syncthreads();                               // cnt32 zeroed
    const int l0 = atomicAdd(&cnt32[(unsigned)s4.x >> 10], 1);   // LDS atomics only
    const int l1 = atomicAdd(&cnt32[(unsigned)s4.y >> 10], 1);
    const int l2 = atomicAdd(&cnt32[(unsigned)s4.z >> 10], 1);
    const int l3 = atomicAdd(&cnt32[(unsigned)s4.w >> 10], 1);

    // deterministic placement: g_bucket[g*SCB*SLOT + b*SLOT + local]
    const unsigned rbase = (unsigned)(b * SLOT);
    unsigned gg;
    gg = (unsigned)s4.x >> 10;
    if (l0 < SLOT) g_bucket[gg * (SCB * SLOT) + rbase + l0] =
        ((unsigned)(s4.x & (NMAX - 1)) << 16) | ((unsigned)(d4.x & (NMAX - 1)) << 2);
    gg = (unsigned)s4.y >> 10;
    if (l1 < SLOT) g_bucket[gg * (SCB * SLOT) + rbase + l1] =
        ((unsigned)(s4.y & (NMAX - 1)) << 16) | ((unsigned)(d4.y & (NMAX - 1)) << 2);
    gg = (unsigned)s4.z >> 10;
    if (l2 < SLOT) g_bucket[gg * (SCB * SLOT) + rbase + l2] =
        ((unsigned)(s4.z & (NMAX - 1)) << 16) | ((unsigned)(d4.z & (NMAX - 1)) << 2);
    gg = (unsigned)s4.w >> 10;
    if (l3 < SLOT) g_bucket[gg * (SCB * SLOT) + rbase + l3] =
        ((unsigned)(s4.w & (NMAX - 1)) << 16) | ((unsigned)(d4.w & (NMAX - 1)) << 2);

    __syncthreads();                               // cnt32 final
    if (tid < 32) g_cnt[(b << 5) + tid] = min(cnt32[tid], SLOT);   // plain store

    // finish y = x.W for this block's 128 nodes
    float s0 = xv0.x * wv.x + xv0.y * wv.y + xv0.z * wv.z + xv0.w * wv.w;
    s0 += __shfl_xor(s0, 4, 8);
    s0 += __shfl_xor(s0, 2, 8);
    s0 += __shfl_xor(s0, 1, 8);
    if (sub == 0) g_y[n0] = s0;
    float s1 = xv1.x * wv.x + xv1.y * wv.y + xv1.z * wv.z + xv1.w * wv.w;
    s1 += __shfl_xor(s1, 4, 8);
    s1 += __shfl_xor(s1, 2, 8);
    s1 += __shfl_xor(s1, 1, 8);
    if (sub == 0) g_y[n1] = s1;
}

__global__ __launch_bounds__(TPB) void
k_solve(const float* __restrict__ h, const float* __restrict__ bias,
        float* __restrict__ out, int L) {
    __shared__ __align__(16) unsigned short csr[NMAX * REG_E];   // 96 KB
    __shared__ int   deg[NMAX];                                  // 4 KB
    __shared__ float v2[2][NMAX];                                // 8 KB (double-buffered)
    __shared__ float ys[NMAX];                                   // 4 KB
    __shared__ unsigned short pos2node[NMAX];                    // 2 KB
    __shared__ int   cntb[SCB];                                  // 1 KB
    __shared__ int   hist[64];
    __shared__ float red[16];
    __shared__ float lh[8];

    const int g   = blockIdx.x;
    const int tid = threadIdx.x;

    deg[tid] = 0;
    if (tid < 64)  hist[tid] = 0;
    if (tid < 8)   lh[tid] = (tid < L) ? h[tid] : 0.0f;
    if (tid < SCB) cntb[tid] = g_cnt[(tid << 5) + g];
    {   // zero this node's CSR slots: stale garbage -> offset 0 (v[0]), masked
        uint4* cz = (uint4*)(csr + (size_t)tid * REG_E);
        #pragma unroll
        for (int i = 0; i < 6; ++i) cz[i] = make_uint4(0u, 0u, 0u, 0u);
    }
    ys[tid] = g_y[(g << 10) + tid];
    __syncthreads();

    // ---- build my graph's CSR in LDS from my bucket region (128 KB) ----
    {
        const unsigned* gb = g_bucket + (size_t)g * (SCB * SLOT);
        for (int i = tid; i < SCB * SLOT; i += TPB) {   // 32 passes; invalid waves execz-skip
            if ((i & (SLOT - 1)) < cntb[i >> 7]) {
                const unsigned pk = gb[i];
                const int s = (int)(pk >> 16);
                const int p = atomicAdd(&deg[s], 1);     // LDS atomic
                if (p < REG_E) csr[s * REG_E + p] = (unsigned short)(pk & 0xFFFFu);
            }
        }
    }
    __syncthreads();

    // ---- counting sort by degree: thread t handles node pos2node[t] ----
    const int myd = min(deg[tid], REG_E);
    atomicAdd(&hist[myd], 1);
    __syncthreads();
    if (tid < 64) {                    // wave-parallel exclusive scan (one wave)
        const int val = hist[tid];
        int inc = val;
        #pragma unroll
        for (int o = 1; o < 64; o <<= 1) {
            const int t = __shfl_up(inc, o, 64);
            if (tid >= o) inc += t;
        }
        hist[tid] = inc - val;
    }
    __syncthreads();
    {
        const int pos = atomicAdd(&hist[myd], 1);
        pos2node[pos] = (unsigned short)tid;
    }
    __syncthreads();

    // ---- stage my node's neighbor list into registers ----
    const int n  = pos2node[tid];
    const int dc = min(deg[n], REG_E);
    unsigned idx[RE_U32];
    {
        const uint4* cp = (const uint4*)(csr + (size_t)n * REG_E);
        #pragma unroll
        for (int i = 0; i < 6; ++i) {
            const uint4 t = cp[i];
            idx[4 * i + 0] = t.x; idx[4 * i + 1] = t.y;
            idx[4 * i + 2] = t.z; idx[4 * i + 3] = t.w;
        }
    }
    const float yreg = ys[n];
    v2[0][tid] = 1.0f;                 // u_0 = ones (tid spans all nodes)
    float vreg = 1.0f;
    float acc  = 0.0f;
    int   cur  = 0;
    __syncthreads();

    // ---- k-loop: 7 sparse matvecs, ONE barrier each (double-buffered v) ----
    for (int k = 0; k < L; ++k) {
        acc += lh[k] * vreg * yreg;
        if (k == L - 1) break;

        const char* base = (const char*)v2[cur];
        float nv = 0.0f;
        #pragma unroll
        for (int i = 0; i < RE_U32; ++i) {   // execz-skips past wave-max (~mean) degree
            if (2 * i < dc) {
                const unsigned p = idx[i];   // two prescaled byte offsets
                nv += *(const float*)(base + (p & 0xFFFFu));
                const float hv = *(const float*)(base + (p >> 16));
                nv += (2 * i + 1 < dc) ? hv : 0.0f;
            }
        }
        v2[cur ^ 1][n] = nv;                 // disjoint from gather source
        vreg = nv;
        __syncthreads();                     // writes visible; also fences buffer re-use
        cur ^= 1;
    }

    // ---- reduction + output ----
    #pragma unroll
    for (int off = 32; off > 0; off >>= 1) acc += __shfl_down(acc, off);
    if ((tid & 63) == 0) red[tid >> 6] = acc;
    __syncthreads();
    if (tid == 0) {
        float t = 0.0f;
        #pragma unroll
        for (int w = 0; w < 16; ++w) t += red[w];
        out[g] = bias[0] + t;
    }
}

extern "C" void kernel_launch(void* const* d_in, const int* in_sizes, int n_in,
                              void* d_out, int out_size, void* d_ws, size_t ws_size,
                              hipStream_t stream) {
    const float* x  = (const float*)d_in[0];
    const int*   ei = (const int*)d_in[1];   // (2,E): row0 = dst global, row1 = src global
    const float* h  = (const float*)d_in[3];
    const float* W  = (const float*)d_in[4];
    const float* b  = (const float*)d_in[5];
    float* out = (float*)d_out;

    const int BN = in_sizes[2];          // 32768
    const int L  = in_sizes[3];          // 8
    const int F  = in_sizes[4];          // 32
    const int E  = in_sizes[1] / 2;      // 524288
    const int B  = out_size;             // 32
    const int N  = BN / B;               // 1024

    // fixed-shape guards (never taken for this problem):
    // scatter grid must be exactly SCB blocks AND cover BN nodes for y.
    if (B > BMAX || N != NMAX || F != 32 || L > 8) return;
    if (E != SCB * SCT * 4 || SCB * 128 != BN) return;

    const int* dst_g = ei;
    const int* src_g = ei + E;

    k_scatter<<<SCB, SCT, 0, stream>>>(dst_g, src_g, x, W);
    k_solve<<<B, TPB, 0, stream>>>(h, b, out, L);
}

// Round 7
// 86.795 us; speedup vs baseline: 1.1470x; 1.1470x over previous
//
#include <hip/hip_runtime.h>

// Two-kernel pipeline: R11's verified compact-bucket scatter + solve with
// register-batched bucket prefetch, free u1=deg round, parallel scan,
// double-buffered v.
//
// R14 post-mortem of R12/R13 (99.6 us, REGRESSED vs R11's 91.6): the
// deterministic per-(block,graph) bucket doubled the solve's stream to a
// sparse 128 KB with a per-iteration LDS-dependent conditional load, and
// scattered the scatter stores. Reverted to R11's compact buckets (global
// reservation atomics measured FINE). New theory for R11's solve cost:
// serial-latency bucket stream (~16 dependent L3 loads/thread at 1 block/CU)
// + serial tid==0 prefix chain + one analytically-free gather round.
//
// R14 changes vs R11 (solve only; scatter verbatim):
//  - bucket prefetch into 20 statically-indexed regs (predicated loads,
//    sentinel 0xFFFFFFFF -> src 65535 -> skipped; 20*1024 covers CAP
//    exactly): all global loads in flight at once, one vmcnt wait.
//  - u1 = deg (u0 = ones => u1[s] = in-degree[s]): k-loop starts at k=2,
//    6 gather rounds instead of 7; h0+h1*deg folded into acc.
//  - wave-parallel __shfl_up exclusive scan for the degree counting sort.
//  - v double-buffered: gather reads v2[cur], write v2[cur^1], ONE barrier
//    per round (disjoint buffers; barrier orders round k's reads before
//    round k+1's writes).

#define BMAX   32
#define NMAX   1024
#define REG_E  48                 // per-node in-edge cap (Poisson(16); P(>48) ~ 1e-10)
#define RE_U32 (REG_E / 2)
#define TPB    1024
#define SCT    512                // scatter threads/block (1 int4 each)
#define CAP    20480              // per-graph bucket cap (mean 16384, sigma ~128)
#define PF     20                 // prefetch regs: PF*TPB == CAP (full coverage)

__device__ __align__(16) unsigned g_bucket[BMAX * CAP];   // 2.62 MB
__device__ int      g_bcnt[BMAX];                         // zero-init; reset by k_solve
__device__ __align__(16) float g_y[BMAX * NMAX];          // 128 KB

__global__ __launch_bounds__(SCT) void
k_scatter(const int* __restrict__ dst_g, const int* __restrict__ src_g,
          const float* __restrict__ x, const float* __restrict__ W) {
    __shared__ int cnt32[32];
    __shared__ int base32[32];
    const int tid = threadIdx.x;
    const int b   = blockIdx.x;

    if (tid < 32) cnt32[tid] = 0;

    // issue all global loads up front (edges + this block's x rows)
    const int  i  = b * SCT + tid;                 // int4 slot; grid covers E/4 exactly
    const int4 d4 = ((const int4*)dst_g)[i];
    const int4 s4 = ((const int4*)src_g)[i];

    const int    sub = tid & 7, grp = tid >> 3;    // 8 lanes per node, 64 nodes/pass
    const float4 wv  = ((const float4*)W)[sub];
    const int    n0  = (b << 7) + grp;             // this block owns 128 nodes
    const int    n1  = n0 + 64;
    const float4 xv0 = ((const float4*)(x + (size_t)n0 * 32))[sub];
    const float4 xv1 = ((const float4*)(x + (size_t)n1 * 32))[sub];

    __syncthreads();                               // cnt32 zeroed
    const int l0 = atomicAdd(&cnt32[(unsigned)s4.x >> 10], 1);   // LDS atomics
    const int l1 = atomicAdd(&cnt32[(unsigned)s4.y >> 10], 1);
    const int l2 = atomicAdd(&cnt32[(unsigned)s4.z >> 10], 1);
    const int l3 = atomicAdd(&cnt32[(unsigned)s4.w >> 10], 1);
    __syncthreads();
    if (tid < 32) base32[tid] = atomicAdd(&g_bcnt[tid], cnt32[tid]);  // 32 global/block
    __syncthreads();

    unsigned gg, sl;
    gg = (unsigned)s4.x >> 10; sl = (unsigned)(base32[gg] + l0);
    if (sl < CAP) g_bucket[gg * CAP + sl] =
        ((unsigned)(s4.x & (NMAX - 1)) << 16) | ((unsigned)(d4.x & (NMAX - 1)) << 2);
    gg = (unsigned)s4.y >> 10; sl = (unsigned)(base32[gg] + l1);
    if (sl < CAP) g_bucket[gg * CAP + sl] =
        ((unsigned)(s4.y & (NMAX - 1)) << 16) | ((unsigned)(d4.y & (NMAX - 1)) << 2);
    gg = (unsigned)s4.z >> 10; sl = (unsigned)(base32[gg] + l2);
    if (sl < CAP) g_bucket[gg * CAP + sl] =
        ((unsigned)(s4.z & (NMAX - 1)) << 16) | ((unsigned)(d4.z & (NMAX - 1)) << 2);
    gg = (unsigned)s4.w >> 10; sl = (unsigned)(base32[gg] + l3);
    if (sl < CAP) g_bucket[gg * CAP + sl] =
        ((unsigned)(s4.w & (NMAX - 1)) << 16) | ((unsigned)(d4.w & (NMAX - 1)) << 2);

    // finish y = x.W for this block's 128 nodes
    float s0 = xv0.x * wv.x + xv0.y * wv.y + xv0.z * wv.z + xv0.w * wv.w;
    s0 += __shfl_xor(s0, 4, 8);
    s0 += __shfl_xor(s0, 2, 8);
    s0 += __shfl_xor(s0, 1, 8);
    if (sub == 0) g_y[n0] = s0;
    float s1 = xv1.x * wv.x + xv1.y * wv.y + xv1.z * wv.z + xv1.w * wv.w;
    s1 += __shfl_xor(s1, 4, 8);
    s1 += __shfl_xor(s1, 2, 8);
    s1 += __shfl_xor(s1, 1, 8);
    if (sub == 0) g_y[n1] = s1;
}

__global__ __launch_bounds__(TPB) void
k_solve(const float* __restrict__ h, const float* __restrict__ bias,
        float* __restrict__ out, int L) {
    __shared__ __align__(16) unsigned short csr[NMAX * REG_E];   // 96 KB
    __shared__ int   deg[NMAX];                                  // 4 KB
    __shared__ float v2[2][NMAX];                                // 8 KB (double-buffered)
    __shared__ float ys[NMAX];                                   // 4 KB
    __shared__ unsigned short pos2node[NMAX];                    // 2 KB
    __shared__ int   hist[64];
    __shared__ float red[16];
    __shared__ float lh[8];

    const int g   = blockIdx.x;
    const int tid = threadIdx.x;

    // read count early; prefetch my bucket entries into registers with
    // STATIC indexing (rule #20) -- all loads in flight, one vmcnt wait.
    const int cnt = min(g_bcnt[g], CAP);
    unsigned ebuf[PF];
    {
        const unsigned* gb = g_bucket + (size_t)g * CAP;
        #pragma unroll
        for (int j = 0; j < PF; ++j) {
            const int i = tid + j * TPB;             // PF*TPB == CAP: full coverage
            ebuf[j] = (i < cnt) ? gb[i] : 0xFFFFFFFFu;   // sentinel: src=65535
        }
    }

    deg[tid] = 0;
    if (tid < 64) hist[tid] = 0;
    if (tid < 8)  lh[tid] = (tid < L) ? h[tid] : 0.0f;
    {   // zero this node's CSR slots: stale garbage -> offset 0 (v[0]), masked
        uint4* cz = (uint4*)(csr + (size_t)tid * REG_E);
        #pragma unroll
        for (int i = 0; i < 6; ++i) cz[i] = make_uint4(0u, 0u, 0u, 0u);
    }
    ys[tid] = g_y[(g << 10) + tid];
    __syncthreads();                   // deg/csr zeroed before build

    // ---- build my graph's CSR in LDS from prefetched registers ----
    #pragma unroll
    for (int j = 0; j < PF; ++j) {
        const unsigned pk = ebuf[j];
        const unsigned s  = pk >> 16;
        if (s < (unsigned)NMAX) {                    // sentinel skipped
            const int p = atomicAdd(&deg[s], 1);     // LDS atomic
            if (p < REG_E) csr[s * REG_E + p] = (unsigned short)(pk & 0xFFFFu);
        }
    }
    __syncthreads();
    if (tid == 0) g_bcnt[g] = 0;       // invariant for next launch

    // ---- counting sort by degree: thread t handles node pos2node[t] ----
    const int myd = min(deg[tid], REG_E);
    atomicAdd(&hist[myd], 1);
    __syncthreads();
    if (tid < 64) {                    // wave-parallel exclusive scan (one wave)
        const int val = hist[tid];
        int inc = val;
        #pragma unroll
        for (int o = 1; o < 64; o <<= 1) {
            const int t = __shfl_up(inc, o, 64);
            if (tid >= o) inc += t;
        }
        hist[tid] = inc - val;
    }
    __syncthreads();
    {
        const int pos = atomicAdd(&hist[myd], 1);
        pos2node[pos] = (unsigned short)tid;
    }
    __syncthreads();

    // ---- stage my node's neighbor list into registers ----
    const int n    = pos2node[tid];
    const int degN = deg[n];
    const int dc   = min(degN, REG_E);
    unsigned idx[RE_U32];
    {
        const uint4* cp = (const uint4*)(csr + (size_t)n * REG_E);
        #pragma unroll
        for (int i = 0; i < 6; ++i) {
            const uint4 t = cp[i];
            idx[4 * i + 0] = t.x; idx[4 * i + 1] = t.y;
            idx[4 * i + 2] = t.z; idx[4 * i + 3] = t.w;
        }
    }
    const float yreg = ys[n];

    // u0 = ones and u1 = in-degree are both FREE (no gather):
    // acc gets h0*<1,y> + h1*<deg,y> contributions; v2[0] starts at u1.
    const float u1 = (float)degN;
    v2[0][n] = u1;
    float acc = lh[0] * yreg + lh[1] * u1 * yreg;
    __syncthreads();                   // v2[0] (= u1) fully written

    // ---- k-loop: rounds k=2..L-1, ONE barrier each (double-buffered v) ----
    int cur = 0;
    for (int k = 2; k < L; ++k) {
        const char* base = (const char*)v2[cur];
        float nv = 0.0f;
        #pragma unroll
        for (int i = 0; i < RE_U32; ++i) {   // execz-skips past wave-max (~mean) degree
            if (2 * i < dc) {
                const unsigned p = idx[i];   // two prescaled byte offsets
                nv += *(const float*)(base + (p & 0xFFFFu));
                const float hv = *(const float*)(base + (p >> 16));
                nv += (2 * i + 1 < dc) ? hv : 0.0f;
            }
        }
        acc += lh[k] * nv * yreg;
        if (k < L - 1) {
            v2[cur ^ 1][n] = nv;             // disjoint from this round's gather source
            __syncthreads();                 // orders round k reads/writes vs round k+1
            cur ^= 1;
        }
    }

    // ---- reduction + output ----
    #pragma unroll
    for (int off = 32; off > 0; off >>= 1) acc += __shfl_down(acc, off);
    if ((tid & 63) == 0) red[tid >> 6] = acc;
    __syncthreads();
    if (tid == 0) {
        float t = 0.0f;
        #pragma unroll
        for (int w = 0; w < 16; ++w) t += red[w];
        out[g] = bias[0] + t;
    }
}

extern "C" void kernel_launch(void* const* d_in, const int* in_sizes, int n_in,
                              void* d_out, int out_size, void* d_ws, size_t ws_size,
                              hipStream_t stream) {
    const float* x  = (const float*)d_in[0];
    const int*   ei = (const int*)d_in[1];   // (2,E): row0 = dst global, row1 = src global
    const float* h  = (const float*)d_in[3];
    const float* W  = (const float*)d_in[4];
    const float* b  = (const float*)d_in[5];
    float* out = (float*)d_out;

    const int BN = in_sizes[2];          // 32768
    const int L  = in_sizes[3];          // 8
    const int F  = in_sizes[4];          // 32
    const int E  = in_sizes[1] / 2;      // 524288
    const int B  = out_size;             // 32
    const int N  = BN / B;               // 1024

    // fixed-shape guards (never taken for this problem):
    // scatter grid must cover E/4 exactly AND its 128-node y slices cover BN.
    if (B > BMAX || N != NMAX || F != 32 || L > 8) return;
    if ((E % (SCT * 4)) != 0) return;
    const int scb = E / (SCT * 4);       // 256
    if (scb * 128 != BN) return;

    const int* dst_g = ei;
    const int* src_g = ei + E;

    k_scatter<<<scb, SCT, 0, stream>>>(dst_g, src_g, x, W);
    k_solve<<<B, TPB, 0, stream>>>(h, b, out, L);
}